// Round 1
// baseline (158.577 us; speedup 1.0000x reference)
//
#include <hip/hip_runtime.h>
#include <stdint.h>

// Problem constants
#define NB 16          // batches
#define NS 4096        // seq
#define NF 256         // token feature dim (n_state)
#define NH 64          // expert bottleneck (n_embd)
#define NEXP 16        // experts

typedef __attribute__((ext_vector_type(8))) short     bf16x8;
typedef __attribute__((ext_vector_type(4))) float     f32x4;
typedef __attribute__((ext_vector_type(2))) unsigned  u32x2;
typedef __attribute__((ext_vector_type(8))) unsigned short u16x8;

// workspace layout (bytes)
#define PART_OFF   0u          // [32][16][256] f32 partial colsums  (524288)
#define GATE_OFF   524288u     // [16][16] f32 gates                 (1024)
#define BIASC_OFF  525312u     // [16][256] f32 combined bias        (16384)
#define W1T_OFF    541696u     // [16] experts x 32768B bf16 W1^T pre-swizzled
#define W2T_OFF    1065984u    // [16] experts x 32768B bf16 W2^T pre-swizzled

__device__ __forceinline__ unsigned short bfr(float f) {
  unsigned u = __float_as_uint(f);
  u += 0x7fffu + ((u >> 16) & 1u);       // RNE to bf16
  return (unsigned short)(u >> 16);
}
__device__ __forceinline__ unsigned pack2(float a, float b) {
  return (unsigned)bfr(a) | ((unsigned)bfr(b) << 16);
}
__device__ __forceinline__ float gelu_f(float v) {
  float u = 0.7978845608028654f * (v + 0.044715f * v * v * v);
  float t = 1.0f - 2.0f / (__expf(2.0f * u) + 1.0f);   // tanh(u)
  return 0.5f * v * (1.0f + t);
}
__device__ __forceinline__ void stage16(const void* g, void* l) {
  __builtin_amdgcn_global_load_lds((const __attribute__((address_space(1))) void*)g,
                                   (__attribute__((address_space(3))) void*)l, 16, 0, 0);
}

// ---------------- kernel 1: per-batch column partial sums of x ----------------
__global__ void k_colsum(const float* __restrict__ x, float* __restrict__ part) {
  const int b  = blockIdx.x >> 5;
  const int ch = blockIdx.x & 31;
  const int f  = threadIdx.x;
  const float* xp = x + ((size_t)b * NS + (size_t)ch * 128) * NF + f;
  float s = 0.0f;
  for (int i = 0; i < 128; ++i) s += xp[(size_t)i * NF];
  part[(size_t)(ch * 16 + b) * NF + f] = s;
}

// ---------------- kernel 2: weight transpose + bf16 convert + pre-swizzle ----
__global__ void k_prep(const float* __restrict__ W1, const float* __restrict__ W2,
                       uint8_t* __restrict__ wsb) {
  const int u = blockIdx.x * 256 + threadIdx.x;   // 0..65535, one 16B unit each
  u16x8 vals;
  if (u < 32768) {                                 // W1T[e][hd=64][k=256]
    const int e  = u >> 11;
    const int r  = u & 2047;
    const int hd = r >> 5;
    const int k0 = (r & 31) * 8;
    const float* src = W1 + (size_t)e * (NF * NH) + (size_t)k0 * NH + hd;
#pragma unroll
    for (int j = 0; j < 8; ++j) vals[j] = bfr(src[(size_t)j * NH]);
    const int dst = (r * 16) ^ ((hd & 7) << 4);
    *(u16x8*)(wsb + W1T_OFF + (size_t)e * 32768 + dst) = vals;
  } else {                                         // W2T[e][f=256][hd=64]
    const int u2 = u - 32768;
    const int e  = u2 >> 11;
    const int r  = u2 & 2047;
    const int f  = r >> 3;
    const int h0 = (r & 7) * 8;
    const float* src = W2 + (size_t)e * (NH * NF) + (size_t)h0 * NF + f;
#pragma unroll
    for (int j = 0; j < 8; ++j) vals[j] = bfr(src[(size_t)j * NF]);
    const int dst = (r * 16) ^ ((f & 7) << 4);
    *(u16x8*)(wsb + W2T_OFF + (size_t)e * 32768 + dst) = vals;
  }
}

// ---------------- kernel 3: gates + combined bias ----------------------------
__global__ void k_gate(const float* __restrict__ Wg, const float* __restrict__ bg,
                       const float* __restrict__ b2, uint8_t* __restrict__ wsb) {
  __shared__ float cs[16][256];
  __shared__ float lg[16][16];
  __shared__ float gs[16][16];
  const float* part  = (const float*)(wsb + PART_OFF);
  float* gate  = (float*)(wsb + GATE_OFF);
  float* biasc = (float*)(wsb + BIASC_OFF);
  const int t = threadIdx.x;
  for (int b = 0; b < 16; ++b) {
    float s = 0.0f;
    for (int ch = 0; ch < 32; ++ch) s += part[(size_t)(ch * 16 + b) * NF + t];
    cs[b][t] = s * (1.0f / 4096.0f);
  }
  __syncthreads();
  {
    const int b = t >> 4, e = t & 15;
    float acc = bg[e];
    for (int f = 0; f < NF; ++f) acc += cs[b][f] * Wg[f * 16 + e];
    lg[b][e] = acc;
  }
  __syncthreads();
  {
    const int b = t >> 4, e = t & 15;
    float m = lg[b][0];
    for (int j = 1; j < 16; ++j) m = fmaxf(m, lg[b][j]);
    float den = 0.0f;
    for (int j = 0; j < 16; ++j) den += __expf(lg[b][j] - m);
    float g = __expf(lg[b][e] - m) / den;
    gate[b * 16 + e] = g;
    gs[b][e] = g;
  }
  __syncthreads();
  for (int b = 0; b < 16; ++b) {
    float acc = 0.0f;
    for (int e = 0; e < 16; ++e) acc += gs[b][e] * b2[e * NF + t];
    biasc[b * NF + t] = acc;
  }
}

// ---------------- kernel 4: fused all-expert FFN ------------------------------
// 512 blocks x 512 threads; block = 128 tokens of one batch; loop 16 experts.
__global__ __launch_bounds__(512, 2)
void k_main(const float* __restrict__ x, const float* __restrict__ b1g,
            const uint8_t* __restrict__ wsb, float* __restrict__ out) {
  __shared__ __align__(16) uint8_t lds[147456];   // w1t[2]:0/32768, w2t[2]:65536/98304, hT:131072

  const int tid  = threadIdx.x;
  const int w    = tid >> 6;
  const int lane = tid & 63;
  const int c    = lane & 15;
  const int q    = lane >> 4;
  const int wh   = w & 1;          // G1: hd half (32)
  const int wt   = w >> 1;         // G1: token quarter (32)
  const int wf2  = w >> 1;         // G2: f slice (64)
  const int wt2  = w & 1;          // G2: token half (64)
  const int blk  = blockIdx.x;
  const int b    = blk >> 5;
  const int swz  = (c & 7) << 4;

  const float* gate_ws = (const float*)(wsb + GATE_OFF) + b * 16;
  const float* biasc   = (const float*)(wsb + BIASC_OFF) + b * NF;
  const uint8_t* w1src = wsb + W1T_OFF;
  const uint8_t* w2src = wsb + W2T_OFF;

  // ---- issue staging of expert 0 (both matrices) ----
#pragma unroll
  for (int i = 0; i < 4; ++i)
    stage16(w1src + i * 8192 + tid * 16, lds + i * 8192 + tid * 16);
#pragma unroll
  for (int i = 0; i < 4; ++i)
    stage16(w2src + i * 8192 + tid * 16, lds + 65536 + i * 8192 + tid * 16);

  // ---- X preload into B-fragments (bf16), overlaps the staging latency ----
  bf16x8 xf[2][8];
  {
    const int row0 = blk * 128 + wt * 32;
#pragma unroll
    for (int nf = 0; nf < 2; ++nf) {
      const float* xp = x + (size_t)(row0 + nf * 16 + c) * NF + q * 8;
#pragma unroll
      for (int ks = 0; ks < 8; ++ks) {
        f32x4 v0 = *(const f32x4*)(xp + ks * 32);
        f32x4 v1 = *(const f32x4*)(xp + ks * 32 + 4);
        bf16x8 t;
        t[0] = (short)bfr(v0[0]); t[1] = (short)bfr(v0[1]);
        t[2] = (short)bfr(v0[2]); t[3] = (short)bfr(v0[3]);
        t[4] = (short)bfr(v1[0]); t[5] = (short)bfr(v1[1]);
        t[6] = (short)bfr(v1[2]); t[7] = (short)bfr(v1[3]);
        xf[nf][ks] = t;
      }
    }
  }

  const f32x4 fzero = {0.0f, 0.0f, 0.0f, 0.0f};
  f32x4 acc2[4][4];
#pragma unroll
  for (int i = 0; i < 4; ++i)
#pragma unroll
    for (int j = 0; j < 4; ++j) acc2[i][j] = fzero;

  __syncthreads();   // expert-0 weights staged (barrier drains vmcnt)

#pragma unroll 1
  for (int e = 0; e < NEXP; ++e) {
    const int p = e & 1;
    const uint8_t* w1l = lds + p * 32768;
    const uint8_t* w2l = lds + 65536 + p * 32768;

    // stage W1T(e+1) into other buffer; drains by the barriers below
    if (e < 15) {
      const uint8_t* src = w1src + (size_t)(e + 1) * 32768;
      uint8_t* dst = lds + (p ^ 1) * 32768;
#pragma unroll
      for (int i = 0; i < 4; ++i)
        stage16(src + i * 8192 + tid * 16, dst + i * 8192 + tid * 16);
    }

    const float gv = gate_ws[e];
    f32x4 b1v[2];
#pragma unroll
    for (int mf = 0; mf < 2; ++mf)
      b1v[mf] = *(const f32x4*)(b1g + e * NH + wh * 32 + mf * 16 + q * 4);

    // ---- GEMM1 (swapped): D[hd][tok] = W1T x X^T ----
    f32x4 acc1[2][2];
    acc1[0][0] = fzero; acc1[0][1] = fzero; acc1[1][0] = fzero; acc1[1][1] = fzero;
#pragma unroll
    for (int ks = 0; ks < 8; ++ks) {
      bf16x8 a0 = *(const bf16x8*)(w1l + ((((wh * 32 + c) * 512) + ks * 64 + q * 16) ^ swz));
      bf16x8 a1 = *(const bf16x8*)(w1l + ((((wh * 32 + 16 + c) * 512) + ks * 64 + q * 16) ^ swz));
      acc1[0][0] = __builtin_amdgcn_mfma_f32_16x16x32_bf16(a0, xf[0][ks], acc1[0][0], 0, 0, 0);
      acc1[0][1] = __builtin_amdgcn_mfma_f32_16x16x32_bf16(a0, xf[1][ks], acc1[0][1], 0, 0, 0);
      acc1[1][0] = __builtin_amdgcn_mfma_f32_16x16x32_bf16(a1, xf[0][ks], acc1[1][0], 0, 0, 0);
      acc1[1][1] = __builtin_amdgcn_mfma_f32_16x16x32_bf16(a1, xf[1][ks], acc1[1][1], 0, 0, 0);
    }

    __syncthreads();   // bar1: prev G2 done with hT; w1t(e+1) drained

    // ---- epilogue1: bias + gelu + gate, pack, write hT[tok][hd] ----
#pragma unroll
    for (int mf = 0; mf < 2; ++mf) {
#pragma unroll
      for (int nf = 0; nf < 2; ++nf) {
        f32x4 hv = acc1[mf][nf] + b1v[mf];
        float g0 = gelu_f(hv[0]) * gv;
        float g1 = gelu_f(hv[1]) * gv;
        float g2 = gelu_f(hv[2]) * gv;
        float g3 = gelu_f(hv[3]) * gv;
        u32x2 hw;
        hw.x = pack2(g0, g1);
        hw.y = pack2(g2, g3);
        const int tok = wt * 32 + nf * 16 + c;
        const int off = ((tok * 128) + wh * 64 + mf * 32 + q * 8) ^ swz;
        *(u32x2*)(lds + 131072 + off) = hw;
      }
    }

    __syncthreads();   // bar2: hT complete

    // ---- GEMM2 (swapped): D[f][tok] += W2T x h^T ----
#pragma unroll
    for (int ks2 = 0; ks2 < 2; ++ks2) {
      bf16x8 bf2[4];
#pragma unroll
      for (int nf2 = 0; nf2 < 4; ++nf2) {
        const int off = (((wt2 * 64 + nf2 * 16 + c) * 128) + ks2 * 64 + q * 16) ^ swz;
        bf2[nf2] = *(const bf16x8*)(lds + 131072 + off);
      }
#pragma unroll
      for (int mf2 = 0; mf2 < 4; ++mf2) {
        const int off = (((wf2 * 64 + mf2 * 16 + c) * 128) + ks2 * 64 + q * 16) ^ swz;
        bf16x8 a2 = *(const bf16x8*)(w2l + off);
#pragma unroll
        for (int nf2 = 0; nf2 < 4; ++nf2)
          acc2[mf2][nf2] = __builtin_amdgcn_mfma_f32_16x16x32_bf16(a2, bf2[nf2], acc2[mf2][nf2], 0, 0, 0);
      }
    }

    // stage W2T(e+1); its readers run after next bar2, drained at next bar1
    if (e < 15) {
      const uint8_t* src = w2src + (size_t)(e + 1) * 32768;
      uint8_t* dst = lds + 65536 + (p ^ 1) * 32768;
#pragma unroll
      for (int i = 0; i < 4; ++i)
        stage16(src + i * 8192 + tid * 16, dst + i * 8192 + tid * 16);
    }
  }

  // ---- output: acc2 + biasc, float4 stores ----
#pragma unroll
  for (int mf2 = 0; mf2 < 4; ++mf2) {
    const int fbase = wf2 * 64 + mf2 * 16 + q * 4;
    f32x4 bc = *(const f32x4*)(biasc + fbase);
#pragma unroll
    for (int nf2 = 0; nf2 < 4; ++nf2) {
      const int token = blk * 128 + wt2 * 64 + nf2 * 16 + c;
      f32x4 o = acc2[mf2][nf2] + bc;
      *(f32x4*)(out + (size_t)token * NF + fbase) = o;
    }
  }
}

// ---------------- host launch -------------------------------------------------
extern "C" void kernel_launch(void* const* d_in, const int* in_sizes, int n_in,
                              void* d_out, int out_size, void* d_ws, size_t ws_size,
                              hipStream_t stream) {
  const float* x  = (const float*)d_in[0];
  const float* W1 = (const float*)d_in[1];
  const float* b1 = (const float*)d_in[2];
  const float* W2 = (const float*)d_in[3];
  const float* b2 = (const float*)d_in[4];
  const float* Wg = (const float*)d_in[5];
  const float* bg = (const float*)d_in[6];
  float* out = (float*)d_out;
  uint8_t* wsb = (uint8_t*)d_ws;

  k_colsum<<<512, 256, 0, stream>>>(x, (float*)(wsb + PART_OFF));
  k_prep<<<256, 256, 0, stream>>>(W1, W2, wsb);
  k_gate<<<1, 256, 0, stream>>>(Wg, bg, b2, wsb);
  k_main<<<512, 512, 0, stream>>>(x, b1, wsb, out);
}

// Round 3
// 127.300 us; speedup vs baseline: 1.2457x; 1.2457x over previous
//
#include <hip/hip_runtime.h>
#include <hip/hip_bf16.h>
#include <stdint.h>

// Problem constants
#define NB 16
#define NS 4096
#define NF 256
#define NH 64
#define NEXP 16

typedef __attribute__((ext_vector_type(8))) short     bf16x8;
typedef __attribute__((ext_vector_type(4))) float     f32x4;
typedef __attribute__((ext_vector_type(2))) unsigned  u32x2;
typedef __attribute__((ext_vector_type(8))) unsigned short u16x8;

// workspace layout (bytes)
#define PART_OFF   0u          // [32][16][256] f32 partial colsums
#define GATE_OFF   524288u     // [16][16] f32 gates
#define BIASC_OFF  525312u     // [16][256] f32 combined bias
#define W1T_OFF    541696u     // [16] x 32768B : [kc8][hd64][64B]
#define W2T_OFF    1065984u    // [16] x 32768B : [hc8][f256][16B]

__device__ __forceinline__ unsigned short bfr(float f) {
  unsigned u = __float_as_uint(f);
  u += 0x7fffu + ((u >> 16) & 1u);
  return (unsigned short)(u >> 16);
}
__device__ __forceinline__ unsigned pk(float a, float b) {
  __hip_bfloat162 t = __float22bfloat162_rn(make_float2(a, b));
  union { __hip_bfloat162 h; unsigned u; } cv; cv.h = t; return cv.u;
}
__device__ __forceinline__ void stage16(const void* g, void* l) {
  __builtin_amdgcn_global_load_lds((const __attribute__((address_space(1))) void*)g,
                                   (__attribute__((address_space(3))) void*)l, 16, 0, 0);
}

// ---------------- kernel 1: colsum (blk<512) + weight prep (blk>=512) --------
__global__ void k_pre(const float* __restrict__ x, const float* __restrict__ W1,
                      const float* __restrict__ W2, uint8_t* __restrict__ wsb) {
  const int blk = blockIdx.x;
  if (blk < 512) {
    const int b  = blk >> 5;
    const int ch = blk & 31;
    const int f  = threadIdx.x;
    const float* xp = x + ((size_t)b * NS + (size_t)ch * 128) * NF + f;
    float s = 0.0f;
    for (int i = 0; i < 128; ++i) s += xp[(size_t)i * NF];
    ((float*)(wsb + PART_OFF))[(size_t)(ch * 16 + b) * NF + f] = s;
    return;
  }
  const int u = (blk - 512) * 256 + threadIdx.x;   // 0..65535 units of 16B
  u16x8 vals;
  if (u < 32768) {
    // W1T unit: u = e*2048 + hd*32 + kc   (k = kc*8 + j)
    const int e  = u >> 11;
    const int r  = u & 2047;
    const int hd = r >> 5;
    const int kc = r & 31;
    const float* src = W1 + (size_t)e * (NF * NH) + (size_t)(kc * 8) * NH + hd;
#pragma unroll
    for (int j = 0; j < 8; ++j) vals[j] = bfr(src[(size_t)j * NH]);
    // dst: e*32768 + (k>>5)*4096 + hd*64 + (k&31)*2
    const int dst = (kc >> 2) * 4096 + hd * 64 + (kc & 3) * 16;
    *(u16x8*)(wsb + W1T_OFF + (size_t)e * 32768 + dst) = vals;
  } else {
    // W2T unit: u2 = e*2048 + f*8 + hc    (hd = hc*8 + j)
    const int u2 = u - 32768;
    const int e  = u2 >> 11;
    const int r  = u2 & 2047;
    const int f  = r >> 3;
    const int hc = r & 7;
    const float* src = W2 + (size_t)e * (NH * NF) + (size_t)(hc * 8) * NF + f;
#pragma unroll
    for (int j = 0; j < 8; ++j) vals[j] = bfr(src[(size_t)j * NF]);
    const int dst = hc * 4096 + f * 16;
    *(u16x8*)(wsb + W2T_OFF + (size_t)e * 32768 + dst) = vals;
  }
}

// ---------------- kernel 2: gates + combined bias ----------------------------
__global__ void k_gate(const float* __restrict__ Wg, const float* __restrict__ bg,
                       const float* __restrict__ b2, uint8_t* __restrict__ wsb) {
  __shared__ float cs[16][256];
  __shared__ float lg[16][16];
  __shared__ float gs[16][16];
  const float* part  = (const float*)(wsb + PART_OFF);
  float* gate  = (float*)(wsb + GATE_OFF);
  float* biasc = (float*)(wsb + BIASC_OFF);
  const int t = threadIdx.x;
  for (int b = 0; b < 16; ++b) {
    float s = 0.0f;
    for (int ch = 0; ch < 32; ++ch) s += part[(size_t)(ch * 16 + b) * NF + t];
    cs[b][t] = s * (1.0f / 4096.0f);
  }
  __syncthreads();
  {
    const int b = t >> 4, e = t & 15;
    float acc = bg[e];
    for (int f = 0; f < NF; ++f) acc += cs[b][f] * Wg[f * 16 + e];
    lg[b][e] = acc;
  }
  __syncthreads();
  {
    const int b = t >> 4, e = t & 15;
    float m = lg[b][0];
    for (int j = 1; j < 16; ++j) m = fmaxf(m, lg[b][j]);
    float den = 0.0f;
    for (int j = 0; j < 16; ++j) den += __expf(lg[b][j] - m);
    float g = __expf(lg[b][e] - m) / den;
    gate[b * 16 + e] = g;
    gs[b][e] = g;
  }
  __syncthreads();
  for (int b = 0; b < 16; ++b) {
    float acc = 0.0f;
    for (int e = 0; e < 16; ++e) acc += gs[b][e] * b2[e * NF + t];
    biasc[b * NF + t] = acc;
  }
}

// ---------------- kernel 3: fused all-expert FFN ------------------------------
// 512 blocks x 512 thr (8 waves); block = 128 tokens of one batch.
// LDS 160KB: W1 dbuf [0,64K), W2 dbuf [64K,128K), hT dbuf [128K,160K).
// Iter e: stage W1(e+1), W2(e); GEMM1(e); GEMM2(e-1); epi(e)->hT[e&1]; 1 barrier.
__global__ __launch_bounds__(512, 2)
void k_main(const float* __restrict__ x, const float* __restrict__ b1g,
            const uint8_t* __restrict__ wsb, float* __restrict__ out) {
  __shared__ __align__(16) uint8_t lds[163840];

  const int tid  = threadIdx.x;
  const int w    = tid >> 6;
  const int lane = tid & 63;
  const int c    = lane & 15;
  const int q    = lane >> 4;
  const int wh   = w & 1;          // G1: hd half (32 rows)
  const int wt   = w >> 1;         // G1: token quarter (32)
  const int wf2  = w >> 1;         // G2: f slice (64)
  const int wt2  = w & 1;          // G2: token half (64)
  const int blk  = blockIdx.x;
  const int b    = blk >> 5;

  const float* gate_ws = (const float*)(wsb + GATE_OFF) + b * 16;
  const float* biasc   = (const float*)(wsb + BIASC_OFF) + b * NF;
  const uint8_t* w1src = wsb + W1T_OFF;
  const uint8_t* w2src = wsb + W2T_OFF;

  // ---- prologue: stage W1(0) into parity 0 ----
#pragma unroll
  for (int i = 0; i < 4; ++i)
    stage16(w1src + i * 8192 + tid * 16, lds + i * 8192 + tid * 16);

  // ---- X preload -> bf16 B-fragments (overlaps staging latency) ----
  bf16x8 xf[2][8];
  {
    const int row0 = blk * 128 + wt * 32;
#pragma unroll
    for (int n = 0; n < 2; ++n) {
      const float* xp = x + (size_t)(row0 + n * 16 + c) * NF + q * 8;
#pragma unroll
      for (int ks = 0; ks < 8; ++ks) {
        f32x4 v0 = *(const f32x4*)(xp + ks * 32);
        f32x4 v1 = *(const f32x4*)(xp + ks * 32 + 4);
        union { unsigned u[4]; bf16x8 v; } cv;
        cv.u[0] = pk(v0[0], v0[1]); cv.u[1] = pk(v0[2], v0[3]);
        cv.u[2] = pk(v1[0], v1[1]); cv.u[3] = pk(v1[2], v1[3]);
        xf[n][ks] = cv.v;
      }
    }
  }

  const f32x4 fzero = {0.0f, 0.0f, 0.0f, 0.0f};
  f32x4 acc2[4][4];
#pragma unroll
  for (int i = 0; i < 4; ++i)
#pragma unroll
    for (int j = 0; j < 4; ++j) acc2[i][j] = fzero;

  __syncthreads();   // W1(0) staged (vmcnt drained)

  const float K1 = -2.3021858962f;      // -2*sqrt(2/pi)*log2(e)
  const float KA = -0.102942243f;       // K1*0.044715

#pragma unroll 1
  for (int e = 0; e < NEXP; ++e) {
    const int p  = e & 1;
    const int pn = p ^ 1;

    // ---- stage W1(e+1) -> parity pn ; stage W2(e) -> parity p ----
    if (e < 15) {
      const uint8_t* src = w1src + (size_t)(e + 1) * 32768;
      uint8_t* dst = lds + pn * 32768;
#pragma unroll
      for (int i = 0; i < 4; ++i)
        stage16(src + i * 8192 + tid * 16, dst + i * 8192 + tid * 16);
    }
    {
      const uint8_t* src = w2src + (size_t)e * 32768;
      uint8_t* dst = lds + 65536 + p * 32768;
#pragma unroll
      for (int i = 0; i < 4; ++i)
        stage16(src + i * 8192 + tid * 16, dst + i * 8192 + tid * 16);
    }

    // ---- GEMM1(e): D[hd][tok] = W1T x X^T, reads W1buf[p] ----
    const uint8_t* w1p = lds + p * 32768;
    f32x4 acc1[2][2];
    acc1[0][0] = fzero; acc1[0][1] = fzero; acc1[1][0] = fzero; acc1[1][1] = fzero;
#pragma unroll
    for (int ks = 0; ks < 8; ++ks) {
      bf16x8 a0 = *(const bf16x8*)(w1p + ks * 4096 + (wh * 32 + c) * 64 + q * 16);
      bf16x8 a1 = *(const bf16x8*)(w1p + ks * 4096 + (wh * 32 + 16 + c) * 64 + q * 16);
      acc1[0][0] = __builtin_amdgcn_mfma_f32_16x16x32_bf16(a0, xf[0][ks], acc1[0][0], 0, 0, 0);
      acc1[0][1] = __builtin_amdgcn_mfma_f32_16x16x32_bf16(a0, xf[1][ks], acc1[0][1], 0, 0, 0);
      acc1[1][0] = __builtin_amdgcn_mfma_f32_16x16x32_bf16(a1, xf[0][ks], acc1[1][0], 0, 0, 0);
      acc1[1][1] = __builtin_amdgcn_mfma_f32_16x16x32_bf16(a1, xf[1][ks], acc1[1][1], 0, 0, 0);
    }

    // ---- GEMM2(e-1): D[f][tok] += W2T x hT, reads W2buf[pn], hT[pn] ----
    if (e > 0) {
      const uint8_t* w2p  = lds + 65536 + pn * 32768;
      const uint8_t* htp2 = lds + 131072 + pn * 16384;
#pragma unroll
      for (int ks2 = 0; ks2 < 2; ++ks2) {
        bf16x8 bb2[4];
#pragma unroll
        for (int n2 = 0; n2 < 4; ++n2)
          bb2[n2] = *(const bf16x8*)(htp2 + (ks2 * 4 + q) * 2048 + (wt2 * 64 + n2 * 16 + c) * 16);
#pragma unroll
        for (int m2 = 0; m2 < 4; ++m2) {
          bf16x8 a2 = *(const bf16x8*)(w2p + (ks2 * 4 + q) * 4096 + (wf2 * 64 + m2 * 16 + c) * 16);
#pragma unroll
          for (int n2 = 0; n2 < 4; ++n2)
            acc2[m2][n2] = __builtin_amdgcn_mfma_f32_16x16x32_bf16(a2, bb2[n2], acc2[m2][n2], 0, 0, 0);
        }
      }
    }

    // ---- epilogue(e): bias + gelu*gate -> bf16 -> hT[p] ----
    {
      const float gv = gate_ws[e];
      uint8_t* htp = lds + 131072 + p * 16384;
      f32x4 b1v[2];
#pragma unroll
      for (int m = 0; m < 2; ++m)
        b1v[m] = *(const f32x4*)(b1g + e * NH + wh * 32 + m * 16 + q * 4);
#pragma unroll
      for (int m = 0; m < 2; ++m) {
#pragma unroll
        for (int n = 0; n < 2; ++n) {
          f32x4 hv = acc1[m][n] + b1v[m];
          float o[4];
#pragma unroll
          for (int r = 0; r < 4; ++r) {
            float xx = hv[r];
            float x2 = xx * xx;
            float tt = fmaf(KA, x2, K1);
            float ez = __builtin_amdgcn_exp2f(xx * tt);
            float rc = __builtin_amdgcn_rcpf(ez + 1.0f);
            o[r] = (gv * xx) * rc;
          }
          u32x2 hw;
          hw.x = pk(o[0], o[1]);
          hw.y = pk(o[2], o[3]);
          const int chunk = wh * 4 + m * 2 + (q >> 1);
          const int tok   = wt * 32 + n * 16 + c;
          *(u32x2*)(htp + chunk * 2048 + tok * 16 + (q & 1) * 8) = hw;
        }
      }
    }

    __syncthreads();
  }

  // ---- final GEMM2(15): parity 1 ----
  {
    const uint8_t* w2p  = lds + 65536 + 32768;
    const uint8_t* htp2 = lds + 131072 + 16384;
#pragma unroll
    for (int ks2 = 0; ks2 < 2; ++ks2) {
      bf16x8 bb2[4];
#pragma unroll
      for (int n2 = 0; n2 < 4; ++n2)
        bb2[n2] = *(const bf16x8*)(htp2 + (ks2 * 4 + q) * 2048 + (wt2 * 64 + n2 * 16 + c) * 16);
#pragma unroll
      for (int m2 = 0; m2 < 4; ++m2) {
        bf16x8 a2 = *(const bf16x8*)(w2p + (ks2 * 4 + q) * 4096 + (wf2 * 64 + m2 * 16 + c) * 16);
#pragma unroll
        for (int n2 = 0; n2 < 4; ++n2)
          acc2[m2][n2] = __builtin_amdgcn_mfma_f32_16x16x32_bf16(a2, bb2[n2], acc2[m2][n2], 0, 0, 0);
      }
    }
  }

  // ---- output: acc2 + biasc ----
#pragma unroll
  for (int m2 = 0; m2 < 4; ++m2) {
    const int fbase = wf2 * 64 + m2 * 16 + q * 4;
    f32x4 bc = *(const f32x4*)(biasc + fbase);
#pragma unroll
    for (int n2 = 0; n2 < 4; ++n2) {
      const int token = blk * 128 + wt2 * 64 + n2 * 16 + c;
      f32x4 o = acc2[m2][n2] + bc;
      *(f32x4*)(out + (size_t)token * NF + fbase) = o;
    }
  }
}

// ---------------- host launch -------------------------------------------------
extern "C" void kernel_launch(void* const* d_in, const int* in_sizes, int n_in,
                              void* d_out, int out_size, void* d_ws, size_t ws_size,
                              hipStream_t stream) {
  const float* x  = (const float*)d_in[0];
  const float* W1 = (const float*)d_in[1];
  const float* b1 = (const float*)d_in[2];
  const float* W2 = (const float*)d_in[3];
  const float* b2 = (const float*)d_in[4];
  const float* Wg = (const float*)d_in[5];
  const float* bg = (const float*)d_in[6];
  float* out = (float*)d_out;
  uint8_t* wsb = (uint8_t*)d_ws;

  k_pre<<<768, 256, 0, stream>>>(x, W1, W2, wsb);
  k_gate<<<1, 256, 0, stream>>>(Wg, bg, b2, wsb);
  k_main<<<512, 512, 0, stream>>>(x, b1, wsb, out);
}